// Round 2
// baseline (114.490 us; speedup 1.0000x reference)
//
#include <hip/hip_runtime.h>

// RoiDeform: inputs (2,1600,1600,3) f32, delta_p (2,4,4,2) f32, k=4, cs=384.
// out[b,bin,r,s,c] = bilinear(img_b, 32 + (bin/4)*384 + s + dp0,
//                                    32 + (bin%4)*384 + s + dp1)[c]
//   -- independent of r (broadcast along r).
//
// FUSED single kernel: each block owns one (b,bin, 8-row chunk). It recomputes
// the bin's 384-sample bilinear row directly into LDS (the 4-tap gathers for a
// bin touch ~2 image rows, shared by all 48 chunk-blocks of that bin -> L2-hot,
// recompute is ~free), then broadcast-stores 8 output rows with non-temporal
// float4 stores. Removes the K1 dispatch, the K1->K2 dependency drain, and all
// d_ws traffic.

// clang-native vector type: __builtin_nontemporal_store rejects HIP_vector_type.
typedef float f32x4 __attribute__((ext_vector_type(4)));

constexpr int B  = 2;
constexpr int H  = 1600;
constexpr int W  = 1600;
constexpr int C  = 3;
constexpr int K  = 4;
constexpr int CS = 384;
constexpr int PL = (H - CS * K) / 2;      // 32
constexpr int ROW_F  = CS * C;            // 1152 floats per sample row
constexpr int ROW_F4 = ROW_F / 4;         // 288 float4 per sample row
constexpr int NBBIN  = B * K * K;         // 32 (b,bin) pairs
constexpr int RCHUNK = 8;                 // output rows written per block
constexpr int NCHUNK = CS / RCHUNK;       // 48 chunks per (b,bin)
constexpr int NSTORE = RCHUNK * ROW_F4 / 256;  // 9 float4 stores per thread

__global__ __launch_bounds__(256) void roideform_fused(
    const float* __restrict__ img,   // (B,H,W,C)
    const float* __restrict__ dp,    // (B,K,K,2)
    float* __restrict__ out)         // (B, K*K, CS, CS, C)
{
    const int bid   = blockIdx.x;
    const int bbin  = bid / NCHUNK;
    const int chunk = bid - bbin * NCHUNK;
    const int b    = bbin >> 4;
    const int bin  = bbin & 15;
    const int i    = bin >> 2;
    const int j    = bin & 3;

    // 16B-aligned LDS row so the store loop reads it as ds_read_b128.
    __shared__ f32x4 row4s[ROW_F4];
    float* row = (float*)row4s;

    const float dp0 = dp[((b * K + i) * K + j) * 2 + 0];
    const float dp1 = dp[((b * K + i) * K + j) * 2 + 1];
    const float* __restrict__ imgb = img + (size_t)b * H * W * C;

    // ---- gather phase: 384 bilinear samples, 256 threads (1-2 samples each)
    for (int s = (int)threadIdx.x; s < CS; s += 256) {
        const float r = (float)(PL + i * CS + s) + dp0;
        const float c = (float)(PL + j * CS + s) + dp1;
        const float r0 = floorf(r), c0 = floorf(c);
        const float rf = r - r0,   cf = c - c0;
        const int ri0 = (int)r0, ci0 = (int)c0;

        float a0 = 0.f, a1 = 0.f, a2 = 0.f;
#pragma unroll
        for (int dr = 0; dr < 2; ++dr) {
            const int  ri = ri0 + dr;
            const float wr = dr ? rf : (1.0f - rf);
            const bool rvalid = (ri >= 0) && (ri < H);
#pragma unroll
            for (int dc = 0; dc < 2; ++dc) {
                const int  ci = ci0 + dc;
                const float wc = dc ? cf : (1.0f - cf);
                if (rvalid && (ci >= 0) && (ci < W)) {
                    const float w = wr * wc;
                    const float* p = imgb + ((size_t)ri * W + ci) * C;
                    a0 += w * p[0];
                    a1 += w * p[1];
                    a2 += w * p[2];
                }
            }
        }
        row[s * C + 0] = a0;
        row[s * C + 1] = a1;
        row[s * C + 2] = a2;
    }
    __syncthreads();

    // ---- broadcast-store phase: 8 output rows = 2304 float4, non-temporal
    f32x4* __restrict__ out4 =
        (f32x4*)out + (size_t)(bbin * CS + chunk * RCHUNK) * ROW_F4;

#pragma unroll
    for (int it = 0; it < NSTORE; ++it) {
        const int t = it * 256 + (int)threadIdx.x;
        __builtin_nontemporal_store(row4s[t % ROW_F4], out4 + t);
    }
}

extern "C" void kernel_launch(void* const* d_in, const int* in_sizes, int n_in,
                              void* d_out, int out_size, void* d_ws, size_t ws_size,
                              hipStream_t stream) {
    const float* img = (const float*)d_in[0];
    const float* dp  = (const float*)d_in[1];
    float* out = (float*)d_out;
    (void)d_ws; (void)ws_size;

    roideform_fused<<<NBBIN * NCHUNK, 256, 0, stream>>>(img, dp, out);
}

// Round 3
// 109.922 us; speedup vs baseline: 1.0416x; 1.0416x over previous
//
#include <hip/hip_runtime.h>

// RoiDeform: inputs (2,1600,1600,3) f32, delta_p (2,4,4,2) f32, k=4, cs=384.
// out[b,bin,r,s,c] = bilinear(img_b, 32 + (bin/4)*384 + s + dp0,
//                                    32 + (bin%4)*384 + s + dp1)[c]
//   -- independent of r (broadcast along r).
//
// FUSED single kernel: each block owns one (b,bin, 16-row chunk). It recomputes
// the bin's 384-sample bilinear row directly into LDS (the 4-tap gathers for a
// bin touch ~18 KB of image, shared by all 24 chunk-blocks of that bin ->
// L2/L3-hot, recompute ~free), then broadcast-stores 16 output rows with
// non-temporal float4 stores (keeps the write-once stream out of L2, so image
// rows stay resident for later blocks of the same bin).
//
// RCHUNK=16 -> 768 blocks = exactly 3 blocks/CU; halves redundant gather work
// vs RCHUNK=8 while NT stores still saturate write BW.

typedef float f32x4 __attribute__((ext_vector_type(4)));

constexpr int B  = 2;
constexpr int H  = 1600;
constexpr int W  = 1600;
constexpr int C  = 3;
constexpr int K  = 4;
constexpr int CS = 384;
constexpr int PL = (H - CS * K) / 2;      // 32
constexpr int ROW_F  = CS * C;            // 1152 floats per sample row
constexpr int ROW_F4 = ROW_F / 4;         // 288 float4 per sample row
constexpr int NBBIN  = B * K * K;         // 32 (b,bin) pairs
constexpr int RCHUNK = 16;                // output rows written per block
constexpr int NCHUNK = CS / RCHUNK;       // 24 chunks per (b,bin)
constexpr int NSTORE = RCHUNK * ROW_F4 / 256;  // 18 float4 stores per thread

__global__ __launch_bounds__(256) void roideform_fused(
    const float* __restrict__ img,   // (B,H,W,C)
    const float* __restrict__ dp,    // (B,K,K,2)
    float* __restrict__ out)         // (B, K*K, CS, CS, C)
{
    const int bid   = blockIdx.x;
    const int bbin  = bid / NCHUNK;
    const int chunk = bid - bbin * NCHUNK;
    const int b    = bbin >> 4;
    const int bin  = bbin & 15;
    const int i    = bin >> 2;
    const int j    = bin & 3;

    // 16B-aligned LDS row so the store loop reads it as ds_read_b128.
    __shared__ f32x4 row4s[ROW_F4];
    float* row = (float*)row4s;

    const float dp0 = dp[((b * K + i) * K + j) * 2 + 0];
    const float dp1 = dp[((b * K + i) * K + j) * 2 + 1];
    const float* __restrict__ imgb = img + (size_t)b * H * W * C;

    // ---- gather phase: 384 bilinear samples, 256 threads (1-2 samples each)
    for (int s = (int)threadIdx.x; s < CS; s += 256) {
        const float r = (float)(PL + i * CS + s) + dp0;
        const float c = (float)(PL + j * CS + s) + dp1;
        const float r0 = floorf(r), c0 = floorf(c);
        const float rf = r - r0,   cf = c - c0;
        const int ri0 = (int)r0, ci0 = (int)c0;

        float a0 = 0.f, a1 = 0.f, a2 = 0.f;
#pragma unroll
        for (int dr = 0; dr < 2; ++dr) {
            const int  ri = ri0 + dr;
            const float wr = dr ? rf : (1.0f - rf);
            const bool rvalid = (ri >= 0) && (ri < H);
#pragma unroll
            for (int dc = 0; dc < 2; ++dc) {
                const int  ci = ci0 + dc;
                const float wc = dc ? cf : (1.0f - cf);
                if (rvalid && (ci >= 0) && (ci < W)) {
                    const float w = wr * wc;
                    const float* p = imgb + ((size_t)ri * W + ci) * C;
                    a0 += w * p[0];
                    a1 += w * p[1];
                    a2 += w * p[2];
                }
            }
        }
        row[s * C + 0] = a0;
        row[s * C + 1] = a1;
        row[s * C + 2] = a2;
    }
    __syncthreads();

    // ---- broadcast-store phase: 16 output rows = 4608 float4, non-temporal.
    // idx = (it*256 + tid) % 288 maintained by branchless subtract-wrap
    // (idx + 256 < 2*288 always, so one conditional subtract suffices).
    f32x4* __restrict__ out4 =
        (f32x4*)out + (size_t)(bbin * CS + chunk * RCHUNK) * ROW_F4;

    int idx = (int)threadIdx.x;  // < 288 already (256 <= 288)
#pragma unroll
    for (int it = 0; it < NSTORE; ++it) {
        __builtin_nontemporal_store(row4s[idx], out4 + it * 256 + (int)threadIdx.x);
        idx += 256;
        if (idx >= ROW_F4) idx -= ROW_F4;
    }
}

extern "C" void kernel_launch(void* const* d_in, const int* in_sizes, int n_in,
                              void* d_out, int out_size, void* d_ws, size_t ws_size,
                              hipStream_t stream) {
    const float* img = (const float*)d_in[0];
    const float* dp  = (const float*)d_in[1];
    float* out = (float*)d_out;
    (void)d_ws; (void)ws_size;

    roideform_fused<<<NBBIN * NCHUNK, 256, 0, stream>>>(img, dp, out);
}